// Round 12
// baseline (570.076 us; speedup 1.0000x reference)
//
#include <hip/hip_runtime.h>

#define DIM 64
#define KC 512
#define BLK 256          // main: 4 waves per block
#define BLKP 256         // prep block size
#define RSB 256          // rescan block size
#define PT 2             // A-tiles (16 points each) per wave -> 32 points/wave
#define CG 64            // centroids per LDS group (8 groups) -> 18 KB LDS
#define NT (CG / 16)     // 4 centroid tiles per group
#define NGRP (KC / CG)   // 8 groups
#define MARGINH 5e-4f    // cert margin on v' scale (error bound ~3.5e-4)
#define LIST_CAP 500000

typedef _Float16 half8   __attribute__((ext_vector_type(8)));
typedef float    floatx4 __attribute__((ext_vector_type(4)));

__device__ __forceinline__ void async_cp16(_Float16* lds_base, const _Float16* g_lane) {
    __builtin_amdgcn_global_load_lds(
        (const __attribute__((address_space(1))) unsigned int*)(g_lane),
        (__attribute__((address_space(3))) unsigned int*)(lds_base),
        16, 0, 0);
}

// Prep: centroid (hi, lo*2048) fp16 frags in MFMA B-stream order + exact fp32
// ||c||^2 in R1 op order + zero rescan counter. Runs every launch.
__global__ __launch_bounds__(BLKP) void kmeans_prep(
    const float* __restrict__ c, _Float16* __restrict__ frH,
    _Float16* __restrict__ frL, float* __restrict__ g_sc2,
    unsigned* __restrict__ rs_count)
{
    const int b = blockIdx.x;
    if (b < 128) {
        const int e  = b * BLKP + threadIdx.x;
        const int cr = e >> 6, d = e & 63;
        const int T  = cr >> 4, ni = cr & 15;
        const int ch = d >> 5, q = (d >> 3) & 3, j = d & 7;
        const int pos = ((T * 2 + ch) * 64 + (q * 16 + ni)) * 8 + j;
        const float f = c[e];
        const _Float16 h = (_Float16)f;
        frH[pos] = h;
        frL[pos] = (_Float16)((f - (float)h) * 2048.0f);
    } else {
        if (b == 128 && threadIdx.x == 0) *rs_count = 0u;
        const int k = (b - 128) * BLKP + threadIdx.x;
        const float* crow = c + (long)k * DIM;
        float s0 = 0.f, s1 = 0.f, s2 = 0.f, s3 = 0.f;
        #pragma unroll
        for (int d = 0; d < DIM; d += 4) {
            s0 = fmaf(crow[d + 0], crow[d + 0], s0);
            s1 = fmaf(crow[d + 1], crow[d + 1], s1);
            s2 = fmaf(crow[d + 2], crow[d + 2], s2);
            s3 = fmaf(crow[d + 3], crow[d + 3], s3);
        }
        g_sc2[k] = (s0 + s1) + (s2 + s3);
    }
}

// Main. R11 analysis: merge VALU 58us and MFMA 47us would overlap to ~65us
// cross-wave, but 4 waves/SIMD (VGPR 116) all hit the same barriers -> 140us.
// PT=2 halves per-wave footprint (A-frags 32 VGPR, state 24) so waves_per_eu(5)
// (VGPR cap 102) fits -> 5 blocks/CU x 4 waves = 20 waves/CU, 5 independent
// blocks de-correlate barrier stalls. CG=64 (18 KB LDS) so LDS fits 5 blocks.
// RA facts: WG=1024 ignores waves_per_eu -> spills (R8-R10); WG<=512 honors it.
__global__ __launch_bounds__(BLK)
__attribute__((amdgpu_waves_per_eu(5)))
void kmeans_mfma(const float* __restrict__ x,
                 const _Float16* __restrict__ frH, const _Float16* __restrict__ frL,
                 const float* __restrict__ g_sc2, int* __restrict__ out,
                 unsigned* __restrict__ rs_count, int* __restrict__ rs_list, int n)
{
    __shared__ _Float16 shH[NT * 2 * 64 * 8];   // 8 KB
    __shared__ _Float16 shL[NT * 2 * 64 * 8];   // 8 KB
    __shared__ float    s_sc2[KC];              // 2 KB

    const int tid  = threadIdx.x;
    const int wave = tid >> 6;
    const int lane = tid & 63;
    const int nidx = lane & 15;
    const int quad = lane >> 4;

    const long jobBase = ((long)blockIdx.x * 4 + wave) * (PT * 16);

    // A fragments (R4-validated construction), PT=2.
    half8 ah[PT][2], al[PT][2];
    #pragma unroll
    for (int pt = 0; pt < PT; ++pt) {
        long row = jobBase + pt * 16 + nidx;
        if (row > (long)n - 1) row = (long)n - 1;
        #pragma unroll
        for (int ch = 0; ch < 2; ++ch) {
            const float* xp = x + row * DIM + ch * 32 + quad * 8;
            float4 v0 = *(const float4*)xp;
            float4 v1 = *(const float4*)(xp + 4);
            float fs[8] = {v0.x, v0.y, v0.z, v0.w, v1.x, v1.y, v1.z, v1.w};
            #pragma unroll
            for (int j = 0; j < 8; ++j) {
                _Float16 h = (_Float16)fs[j];
                ah[pt][ch][j] = h;
                al[pt][ch][j] = (_Float16)((fs[j] - (float)h) * 2048.0f);
            }
        }
    }

    // argmax state over v' = dot - c2/2 (argmax v' == argmin d2).
    float best[PT][4], sec[PT][4];
    int   bidx[PT][4];
    #pragma unroll
    for (int pt = 0; pt < PT; ++pt)
        #pragma unroll
        for (int r = 0; r < 4; ++r) {
            best[pt][r] = -3.402823466e38f;
            sec[pt][r]  = -3.402823466e38f;
            bidx[pt][r] = 0;
        }

    for (int g = 0; g < NGRP; ++g) {
        if (g) __syncthreads();

        {   // stage group g: 8 KB hi + 8 KB lo; 512 chunks each, 2 rounds/wave
            const _Float16* srcH = frH + (long)g * (NT * 2 * 64 * 8);
            const _Float16* srcL = frL + (long)g * (NT * 2 * 64 * 8);
            #pragma unroll
            for (int ii = 0; ii < 2; ++ii) {
                const int chunk = (ii * 4 + wave) * 64;   // wave-uniform base
                async_cp16(shH + (long)chunk * 8, srcH + (long)(chunk + lane) * 8);
                async_cp16(shL + (long)chunk * 8, srcL + (long)(chunk + lane) * 8);
            }
        }
        if (g == 0) {
            for (int k2 = tid; k2 < KC; k2 += BLK) s_sc2[k2] = g_sc2[k2];
        }
        __syncthreads();

        #pragma unroll 2
        for (int t = 0; t < NT; ++t) {
            const half8 bh0 = *(const half8*)&shH[((t * 2 + 0) * 64 + lane) * 8];
            const half8 bh1 = *(const half8*)&shH[((t * 2 + 1) * 64 + lane) * 8];
            const half8 bl0 = *(const half8*)&shL[((t * 2 + 0) * 64 + lane) * 8];
            const half8 bl1 = *(const half8*)&shL[((t * 2 + 1) * 64 + lane) * 8];
            const float negh = -0.5f * s_sc2[g * CG + t * 16 + nidx]; // -c2/2
            const int   kidx = g * CG + t * 16 + nidx;
            #pragma unroll
            for (int pt = 0; pt < PT; ++pt) {
                floatx4 am = {negh, negh, negh, negh};
                floatx4 ac = {0.f, 0.f, 0.f, 0.f};
                am = __builtin_amdgcn_mfma_f32_16x16x32_f16(ah[pt][0], bh0, am, 0, 0, 0);
                am = __builtin_amdgcn_mfma_f32_16x16x32_f16(ah[pt][1], bh1, am, 0, 0, 0);
                ac = __builtin_amdgcn_mfma_f32_16x16x32_f16(ah[pt][0], bl0, ac, 0, 0, 0);
                ac = __builtin_amdgcn_mfma_f32_16x16x32_f16(ah[pt][1], bl1, ac, 0, 0, 0);
                ac = __builtin_amdgcn_mfma_f32_16x16x32_f16(al[pt][0], bh0, ac, 0, 0, 0);
                ac = __builtin_amdgcn_mfma_f32_16x16x32_f16(al[pt][1], bh1, ac, 0, 0, 0);
                const floatx4 vv = am + ac * 4.8828125e-4f;    // v'
                #pragma unroll
                for (int r = 0; r < 4; ++r) {
                    const bool gt = vv[r] > best[pt][r];       // strict > : first-idx ties
                    // exact identity: med3(sec, vv, best_old) == max(sec, min(vv, best_old))
                    sec[pt][r]  = __builtin_amdgcn_fmed3f(sec[pt][r], vv[r], best[pt][r]);
                    best[pt][r] = fmaxf(best[pt][r], vv[r]);
                    bidx[pt][r] = gt ? kidx : bidx[pt][r];
                }
            }
        }
    }

    // butterfly over the 16 lanes (n) of each quad — argmax, smaller idx on ties
    #pragma unroll
    for (int off = 1; off < 16; off <<= 1) {
        #pragma unroll
        for (int pt = 0; pt < PT; ++pt)
            #pragma unroll
            for (int r = 0; r < 4; ++r) {
                const float ob = __shfl_xor(best[pt][r], off, 64);
                const int   oi = __shfl_xor(bidx[pt][r], off, 64);
                const float os = __shfl_xor(sec[pt][r],  off, 64);
                const bool take = (ob > best[pt][r]) ||
                                  (ob == best[pt][r] && oi < bidx[pt][r]);
                const float loser = take ? best[pt][r] : ob;
                sec[pt][r]  = fmaxf(fmaxf(sec[pt][r], os), loser);
                best[pt][r] = take ? ob : best[pt][r];
                bidx[pt][r] = take ? oi : bidx[pt][r];
            }
    }

    // write: lanes nidx 0..7 own (pt_w = nidx>>2, r_w = nidx&3) at row quad*4+r_w
    const int pt_w = nidx >> 2;    // 0..1 used; nidx >= 8 idle
    const int r_w  = nidx & 3;
    float b = 0.f, s = 0.f; int bi = 0;
    #pragma unroll
    for (int pt = 0; pt < PT; ++pt)
        #pragma unroll
        for (int r = 0; r < 4; ++r) {
            const bool m = (pt == pt_w) && (r == r_w);
            b  = m ? best[pt][r] : b;
            s  = m ? sec[pt][r]  : s;
            bi = m ? bidx[pt][r] : bi;
        }
    const long p = jobBase + (long)pt_w * 16 + quad * 4 + r_w;

    if (nidx < 8 && p < n) {
        out[p] = bi;                        // exact when certified
        if (!(b - s > MARGINH)) {           // uncertified -> deferred exact rescan
            const unsigned idx = atomicAdd(rs_count, 1u);
            if (idx < LIST_CAP) rs_list[idx] = (int)p;
        }
    }
}

// Exact rescan, LDS-staged: ct4[d4*513 + k] holds c[k][4d4..4d4+3].
// Stride 513 == 1 (mod 32 banks) -> conflict-free writes AND column reads.
// fma chains bit-identical to R1.
__global__ __launch_bounds__(RSB) void kmeans_rescan(
    const float* __restrict__ x, const float* __restrict__ c,
    const float* __restrict__ g_sc2, const unsigned* __restrict__ rs_count,
    const int* __restrict__ rs_list, int* __restrict__ out)
{
    __shared__ float4 ct4[16 * 513];   // 128.25 KB
    __shared__ float  s_c2[KC];        // 2 KB

    const int tid = threadIdx.x;
    for (int e = tid; e < KC * 16; e += RSB) {          // coalesced row-chunk reads
        const int k = e >> 4, d4 = e & 15;
        ct4[d4 * 513 + k] = *(const float4*)(c + (long)k * DIM + d4 * 4);
    }
    for (int k = tid; k < KC; k += RSB) s_c2[k] = g_sc2[k];
    __syncthreads();

    const int lane  = tid & 63;
    const int gwave = blockIdx.x * (RSB / 64) + (tid >> 6);
    const int nwave = gridDim.x * (RSB / 64);
    unsigned cnt = *rs_count;
    if (cnt > LIST_CAP) cnt = LIST_CAP;

    for (unsigned j = gwave; j < cnt; j += nwave) {
        const int p = rs_list[j];
        const float* xrow = x + (long)p * DIM;          // wave-uniform -> s_load

        float x20 = 0.f, x21 = 0.f, x22 = 0.f, x23 = 0.f;
        #pragma unroll
        for (int d = 0; d < DIM; d += 4) {
            x20 = fmaf(xrow[d + 0], xrow[d + 0], x20);
            x21 = fmaf(xrow[d + 1], xrow[d + 1], x21);
            x22 = fmaf(xrow[d + 2], xrow[d + 2], x22);
            x23 = fmaf(xrow[d + 3], xrow[d + 3], x23);
        }
        const float x2 = (x20 + x21) + (x22 + x23);

        float bb = 3.402823466e38f; int bbi = 0x7fffffff;
        #pragma unroll
        for (int kk = 0; kk < 8; ++kk) {
            const int k = kk * 64 + lane;               // distinct ks; lex reduce handles order
            float d0 = 0.f, d1 = 0.f, d2a = 0.f, d3 = 0.f;
            #pragma unroll
            for (int d4 = 0; d4 < 16; ++d4) {
                const float4 q = ct4[d4 * 513 + k];     // ds_read_b128, conflict-free
                d0  = fmaf(q.x, xrow[4 * d4 + 0], d0);
                d1  = fmaf(q.y, xrow[4 * d4 + 1], d1);
                d2a = fmaf(q.z, xrow[4 * d4 + 2], d2a);
                d3  = fmaf(q.w, xrow[4 * d4 + 3], d3);
            }
            const float dot = (d0 + d1) + (d2a + d3);
            float d2v = (x2 + s_c2[k]) - 2.0f * dot;
            d2v = fmaxf(d2v, 0.0f);
            const bool l2 = (d2v < bb) || (d2v == bb && k < bbi);
            bb  = l2 ? d2v : bb;
            bbi = l2 ? k   : bbi;
        }
        #pragma unroll
        for (int off = 1; off < 64; off <<= 1) {
            const float ob = __shfl_xor(bb, off, 64);
            const int   oi = __shfl_xor(bbi, off, 64);
            const bool take = (ob < bb) || (ob == bb && oi < bbi);
            bb  = take ? ob : bb;
            bbi = take ? oi : bbi;
        }
        if (lane == 0) out[p] = bbi;
    }
}

extern "C" void kernel_launch(void* const* d_in, const int* in_sizes, int n_in,
                              void* d_out, int out_size, void* d_ws, size_t ws_size,
                              hipStream_t stream) {
    const float* x = (const float*)d_in[0];   // [N, 64] fp32
    const float* c = (const float*)d_in[1];   // [512, 64] fp32
    int* out = (int*)d_out;                   // [N] int32 labels
    const int n = in_sizes[0] / DIM;

    _Float16* frH   = (_Float16*)d_ws;                 // 64 KB
    _Float16* frL   = frH + (KC * DIM);                // 64 KB
    float*    gsc2  = (float*)(frL + (KC * DIM));      // 2 KB
    unsigned* cnt   = (unsigned*)(gsc2 + KC);          // 16 B slot
    int*      rlist = (int*)(cnt + 4);                 // <= 2 MB

    kmeans_prep<<<130, BLKP, 0, stream>>>(c, frH, frL, gsc2, cnt);

    const int jobs   = (n + PT * 16 - 1) / (PT * 16);  // 32 points per wave
    const int blocks = (jobs + 3) / 4;                 // 4 waves per block
    kmeans_mfma<<<blocks, BLK, 0, stream>>>(x, frH, frL, gsc2, out, cnt, rlist, n);

    kmeans_rescan<<<256, RSB, 0, stream>>>(x, c, gsc2, cnt, rlist, out);
}

// Round 13
// 285.680 us; speedup vs baseline: 1.9955x; 1.9955x over previous
//
#include <hip/hip_runtime.h>

#define DIM 64
#define KC 512
#define BLK 256          // main: 4 waves per block
#define BLKP 256         // prep block size
#define RSB 256          // rescan block size
#define PT 2             // A-tiles (16 points each) per wave -> 32 points/wave
#define CG 64            // centroids per LDS group (8 groups) -> 18 KB LDS
#define NT (CG / 16)     // 4 centroid tiles per group
#define NGRP (KC / CG)   // 8 groups
#define MARGINH 5e-4f    // cert margin on v' scale (error bound ~3.5e-4; R12 passed)
#define LIST_CAP 500000

typedef _Float16 half8   __attribute__((ext_vector_type(8)));
typedef float    floatx4 __attribute__((ext_vector_type(4)));

__device__ __forceinline__ void async_cp16(_Float16* lds_base, const _Float16* g_lane) {
    __builtin_amdgcn_global_load_lds(
        (const __attribute__((address_space(1))) unsigned int*)(g_lane),
        (__attribute__((address_space(3))) unsigned int*)(lds_base),
        16, 0, 0);
}

// Prep: centroid (hi, lo*2048) fp16 frags in MFMA B-stream order + exact fp32
// ||c||^2 in R1 op order + zero rescan counter. Runs every launch.
__global__ __launch_bounds__(BLKP) void kmeans_prep(
    const float* __restrict__ c, _Float16* __restrict__ frH,
    _Float16* __restrict__ frL, float* __restrict__ g_sc2,
    unsigned* __restrict__ rs_count)
{
    const int b = blockIdx.x;
    if (b < 128) {
        const int e  = b * BLKP + threadIdx.x;
        const int cr = e >> 6, d = e & 63;
        const int T  = cr >> 4, ni = cr & 15;
        const int ch = d >> 5, q = (d >> 3) & 3, j = d & 7;
        const int pos = ((T * 2 + ch) * 64 + (q * 16 + ni)) * 8 + j;
        const float f = c[e];
        const _Float16 h = (_Float16)f;
        frH[pos] = h;
        frL[pos] = (_Float16)((f - (float)h) * 2048.0f);
    } else {
        if (b == 128 && threadIdx.x == 0) *rs_count = 0u;
        const int k = (b - 128) * BLKP + threadIdx.x;
        const float* crow = c + (long)k * DIM;
        float s0 = 0.f, s1 = 0.f, s2 = 0.f, s3 = 0.f;
        #pragma unroll
        for (int d = 0; d < DIM; d += 4) {
            s0 = fmaf(crow[d + 0], crow[d + 0], s0);
            s1 = fmaf(crow[d + 1], crow[d + 1], s1);
            s2 = fmaf(crow[d + 2], crow[d + 2], s2);
            s3 = fmaf(crow[d + 3], crow[d + 3], s3);
        }
        g_sc2[k] = (s0 + s1) + (s2 + s3);
    }
}

// Main. RA table (measured): WG=256+waves_per_eu(2) -> natural VGPR 100-124,
// NO spill (R4-R7, R11). waves_per_eu(5) -> squeeze to 48 + 170 MB spills
// (R12). WG=1024 -> attribute ignored, 64 + spills (R8-R10). ONLY (2) at
// WG<=512 is safe. PT=2 shrinks natural footprint to ~90 VGPR so (2) should
// yield 5 waves/SIMD; CG=64 (18 KB LDS) lets 5 blocks/CU co-reside.
__global__ __launch_bounds__(BLK)
__attribute__((amdgpu_waves_per_eu(2)))
void kmeans_mfma(const float* __restrict__ x,
                 const _Float16* __restrict__ frH, const _Float16* __restrict__ frL,
                 const float* __restrict__ g_sc2, int* __restrict__ out,
                 unsigned* __restrict__ rs_count, int* __restrict__ rs_list, int n)
{
    __shared__ _Float16 shH[NT * 2 * 64 * 8];   // 8 KB
    __shared__ _Float16 shL[NT * 2 * 64 * 8];   // 8 KB
    __shared__ float    s_sc2[KC];              // 2 KB

    const int tid  = threadIdx.x;
    const int wave = tid >> 6;
    const int lane = tid & 63;
    const int nidx = lane & 15;
    const int quad = lane >> 4;

    const long jobBase = ((long)blockIdx.x * 4 + wave) * (PT * 16);

    // A fragments (R4-validated construction), PT=2.
    half8 ah[PT][2], al[PT][2];
    #pragma unroll
    for (int pt = 0; pt < PT; ++pt) {
        long row = jobBase + pt * 16 + nidx;
        if (row > (long)n - 1) row = (long)n - 1;
        #pragma unroll
        for (int ch = 0; ch < 2; ++ch) {
            const float* xp = x + row * DIM + ch * 32 + quad * 8;
            float4 v0 = *(const float4*)xp;
            float4 v1 = *(const float4*)(xp + 4);
            float fs[8] = {v0.x, v0.y, v0.z, v0.w, v1.x, v1.y, v1.z, v1.w};
            #pragma unroll
            for (int j = 0; j < 8; ++j) {
                _Float16 h = (_Float16)fs[j];
                ah[pt][ch][j] = h;
                al[pt][ch][j] = (_Float16)((fs[j] - (float)h) * 2048.0f);
            }
        }
    }

    // argmax state over v' = dot - c2/2 (argmax v' == argmin d2).
    float best[PT][4], sec[PT][4];
    int   bidx[PT][4];
    #pragma unroll
    for (int pt = 0; pt < PT; ++pt)
        #pragma unroll
        for (int r = 0; r < 4; ++r) {
            best[pt][r] = -3.402823466e38f;
            sec[pt][r]  = -3.402823466e38f;
            bidx[pt][r] = 0;
        }

    for (int g = 0; g < NGRP; ++g) {
        if (g) __syncthreads();

        {   // stage group g: 8 KB hi + 8 KB lo; 512 chunks each, 2 rounds/wave
            const _Float16* srcH = frH + (long)g * (NT * 2 * 64 * 8);
            const _Float16* srcL = frL + (long)g * (NT * 2 * 64 * 8);
            #pragma unroll
            for (int ii = 0; ii < 2; ++ii) {
                const int chunk = (ii * 4 + wave) * 64;   // wave-uniform base
                async_cp16(shH + (long)chunk * 8, srcH + (long)(chunk + lane) * 8);
                async_cp16(shL + (long)chunk * 8, srcL + (long)(chunk + lane) * 8);
            }
        }
        if (g == 0) {
            for (int k2 = tid; k2 < KC; k2 += BLK) s_sc2[k2] = g_sc2[k2];
        }
        __syncthreads();

        #pragma unroll 2
        for (int t = 0; t < NT; ++t) {
            const half8 bh0 = *(const half8*)&shH[((t * 2 + 0) * 64 + lane) * 8];
            const half8 bh1 = *(const half8*)&shH[((t * 2 + 1) * 64 + lane) * 8];
            const half8 bl0 = *(const half8*)&shL[((t * 2 + 0) * 64 + lane) * 8];
            const half8 bl1 = *(const half8*)&shL[((t * 2 + 1) * 64 + lane) * 8];
            const float negh = -0.5f * s_sc2[g * CG + t * 16 + nidx]; // -c2/2
            const int   kidx = g * CG + t * 16 + nidx;
            #pragma unroll
            for (int pt = 0; pt < PT; ++pt) {
                floatx4 am = {negh, negh, negh, negh};
                floatx4 ac = {0.f, 0.f, 0.f, 0.f};
                am = __builtin_amdgcn_mfma_f32_16x16x32_f16(ah[pt][0], bh0, am, 0, 0, 0);
                am = __builtin_amdgcn_mfma_f32_16x16x32_f16(ah[pt][1], bh1, am, 0, 0, 0);
                ac = __builtin_amdgcn_mfma_f32_16x16x32_f16(ah[pt][0], bl0, ac, 0, 0, 0);
                ac = __builtin_amdgcn_mfma_f32_16x16x32_f16(ah[pt][1], bl1, ac, 0, 0, 0);
                ac = __builtin_amdgcn_mfma_f32_16x16x32_f16(al[pt][0], bh0, ac, 0, 0, 0);
                ac = __builtin_amdgcn_mfma_f32_16x16x32_f16(al[pt][1], bh1, ac, 0, 0, 0);
                const floatx4 vv = am + ac * 4.8828125e-4f;    // v'
                #pragma unroll
                for (int r = 0; r < 4; ++r) {
                    const bool gt = vv[r] > best[pt][r];       // strict > : first-idx ties
                    // exact identity: med3(sec, vv, best_old) == max(sec, min(vv, best_old))
                    sec[pt][r]  = __builtin_amdgcn_fmed3f(sec[pt][r], vv[r], best[pt][r]);
                    best[pt][r] = fmaxf(best[pt][r], vv[r]);
                    bidx[pt][r] = gt ? kidx : bidx[pt][r];
                }
            }
        }
    }

    // butterfly over the 16 lanes (n) of each quad — argmax, smaller idx on ties
    #pragma unroll
    for (int off = 1; off < 16; off <<= 1) {
        #pragma unroll
        for (int pt = 0; pt < PT; ++pt)
            #pragma unroll
            for (int r = 0; r < 4; ++r) {
                const float ob = __shfl_xor(best[pt][r], off, 64);
                const int   oi = __shfl_xor(bidx[pt][r], off, 64);
                const float os = __shfl_xor(sec[pt][r],  off, 64);
                const bool take = (ob > best[pt][r]) ||
                                  (ob == best[pt][r] && oi < bidx[pt][r]);
                const float loser = take ? best[pt][r] : ob;
                sec[pt][r]  = fmaxf(fmaxf(sec[pt][r], os), loser);
                best[pt][r] = take ? ob : best[pt][r];
                bidx[pt][r] = take ? oi : bidx[pt][r];
            }
    }

    // write: lanes nidx 0..7 own (pt_w = nidx>>2, r_w = nidx&3) at row quad*4+r_w
    const int pt_w = nidx >> 2;    // 0..1 used; nidx >= 8 idle
    const int r_w  = nidx & 3;
    float b = 0.f, s = 0.f; int bi = 0;
    #pragma unroll
    for (int pt = 0; pt < PT; ++pt)
        #pragma unroll
        for (int r = 0; r < 4; ++r) {
            const bool m = (pt == pt_w) && (r == r_w);
            b  = m ? best[pt][r] : b;
            s  = m ? sec[pt][r]  : s;
            bi = m ? bidx[pt][r] : bi;
        }
    const long p = jobBase + (long)pt_w * 16 + quad * 4 + r_w;

    if (nidx < 8 && p < n) {
        out[p] = bi;                        // exact when certified
        if (!(b - s > MARGINH)) {           // uncertified -> deferred exact rescan
            const unsigned idx = atomicAdd(rs_count, 1u);
            if (idx < LIST_CAP) rs_list[idx] = (int)p;
        }
    }
}

// Exact rescan, LDS-staged: ct4[d4*513 + k] holds c[k][4d4..4d4+3].
// Stride 513 == 1 (mod 32 banks) -> conflict-free writes AND column reads.
// fma chains bit-identical to R1.
__global__ __launch_bounds__(RSB) void kmeans_rescan(
    const float* __restrict__ x, const float* __restrict__ c,
    const float* __restrict__ g_sc2, const unsigned* __restrict__ rs_count,
    const int* __restrict__ rs_list, int* __restrict__ out)
{
    __shared__ float4 ct4[16 * 513];   // 128.25 KB
    __shared__ float  s_c2[KC];        // 2 KB

    const int tid = threadIdx.x;
    for (int e = tid; e < KC * 16; e += RSB) {          // coalesced row-chunk reads
        const int k = e >> 4, d4 = e & 15;
        ct4[d4 * 513 + k] = *(const float4*)(c + (long)k * DIM + d4 * 4);
    }
    for (int k = tid; k < KC; k += RSB) s_c2[k] = g_sc2[k];
    __syncthreads();

    const int lane  = tid & 63;
    const int gwave = blockIdx.x * (RSB / 64) + (tid >> 6);
    const int nwave = gridDim.x * (RSB / 64);
    unsigned cnt = *rs_count;
    if (cnt > LIST_CAP) cnt = LIST_CAP;

    for (unsigned j = gwave; j < cnt; j += nwave) {
        const int p = rs_list[j];
        const float* xrow = x + (long)p * DIM;          // wave-uniform -> s_load

        float x20 = 0.f, x21 = 0.f, x22 = 0.f, x23 = 0.f;
        #pragma unroll
        for (int d = 0; d < DIM; d += 4) {
            x20 = fmaf(xrow[d + 0], xrow[d + 0], x20);
            x21 = fmaf(xrow[d + 1], xrow[d + 1], x21);
            x22 = fmaf(xrow[d + 2], xrow[d + 2], x22);
            x23 = fmaf(xrow[d + 3], xrow[d + 3], x23);
        }
        const float x2 = (x20 + x21) + (x22 + x23);

        float bb = 3.402823466e38f; int bbi = 0x7fffffff;
        #pragma unroll
        for (int kk = 0; kk < 8; ++kk) {
            const int k = kk * 64 + lane;               // distinct ks; lex reduce handles order
            float d0 = 0.f, d1 = 0.f, d2a = 0.f, d3 = 0.f;
            #pragma unroll
            for (int d4 = 0; d4 < 16; ++d4) {
                const float4 q = ct4[d4 * 513 + k];     // ds_read_b128, conflict-free
                d0  = fmaf(q.x, xrow[4 * d4 + 0], d0);
                d1  = fmaf(q.y, xrow[4 * d4 + 1], d1);
                d2a = fmaf(q.z, xrow[4 * d4 + 2], d2a);
                d3  = fmaf(q.w, xrow[4 * d4 + 3], d3);
            }
            const float dot = (d0 + d1) + (d2a + d3);
            float d2v = (x2 + s_c2[k]) - 2.0f * dot;
            d2v = fmaxf(d2v, 0.0f);
            const bool l2 = (d2v < bb) || (d2v == bb && k < bbi);
            bb  = l2 ? d2v : bb;
            bbi = l2 ? k   : bbi;
        }
        #pragma unroll
        for (int off = 1; off < 64; off <<= 1) {
            const float ob = __shfl_xor(bb, off, 64);
            const int   oi = __shfl_xor(bbi, off, 64);
            const bool take = (ob < bb) || (ob == bb && oi < bbi);
            bb  = take ? ob : bb;
            bbi = take ? oi : bbi;
        }
        if (lane == 0) out[p] = bbi;
    }
}

extern "C" void kernel_launch(void* const* d_in, const int* in_sizes, int n_in,
                              void* d_out, int out_size, void* d_ws, size_t ws_size,
                              hipStream_t stream) {
    const float* x = (const float*)d_in[0];   // [N, 64] fp32
    const float* c = (const float*)d_in[1];   // [512, 64] fp32
    int* out = (int*)d_out;                   // [N] int32 labels
    const int n = in_sizes[0] / DIM;

    _Float16* frH   = (_Float16*)d_ws;                 // 64 KB
    _Float16* frL   = frH + (KC * DIM);                // 64 KB
    float*    gsc2  = (float*)(frL + (KC * DIM));      // 2 KB
    unsigned* cnt   = (unsigned*)(gsc2 + KC);          // 16 B slot
    int*      rlist = (int*)(cnt + 4);                 // <= 2 MB

    kmeans_prep<<<130, BLKP, 0, stream>>>(c, frH, frL, gsc2, cnt);

    const int jobs   = (n + PT * 16 - 1) / (PT * 16);  // 32 points per wave
    const int blocks = (jobs + 3) / 4;                 // 4 waves per block
    kmeans_mfma<<<blocks, BLK, 0, stream>>>(x, frH, frL, gsc2, out, cnt, rlist, n);

    kmeans_rescan<<<256, RSB, 0, stream>>>(x, c, gsc2, cnt, rlist, out);
}